// Round 2
// baseline (813.958 us; speedup 1.0000x reference)
//
#include <hip/hip_runtime.h>
#include <hip/hip_cooperative_groups.h>

namespace cg = cooperative_groups;

#define KK 32
#define BATCH 512
#define DD 2048
#define SLABF (KK * BATCH)  // floats per node slab, layout [k][batch] (transposed!)

// ---------------------------------------------------------------------------
// Per-lane full-K node: p[32] (registers) -> log_matmul_exp result, in place.
// W access is wave-uniform -> scalar loads (SMEM pipe). Full unroll so the
// compiler can pipeline s_load_dwordx16 across the whole node.
// ---------------------------------------------------------------------------
__device__ __forceinline__ void node32(float p[KK], const float* __restrict__ Wn) {
  float t[16];
#pragma unroll
  for (int i = 0; i < 16; ++i) t[i] = fmaxf(p[2 * i], p[2 * i + 1]);
#pragma unroll
  for (int s = 8; s >= 1; s >>= 1)
#pragma unroll
    for (int i = 0; i < s; ++i) t[i] = fmaxf(t[i], t[i + s]);
  const float m = t[0];

#pragma unroll
  for (int i = 0; i < KK; ++i) p[i] = __expf(p[i] - m);

  float acc[KK];
#pragma unroll
  for (int j = 0; j < KK; ++j) acc[j] = 0.0f;

#pragma unroll
  for (int i = 0; i < KK; ++i) {
    const float ei = p[i];
#pragma unroll
    for (int j = 0; j < KK; ++j) acc[j] = fmaf(ei, Wn[i * KK + j], acc[j]);
  }

#pragma unroll
  for (int j = 0; j < KK; ++j) p[j] = __logf(acc[j]) + m;
}

// ---------------------------------------------------------------------------
// kern1 load pipeline: a leaf PAIR is 2*32 contiguous floats (256 B).
// issue_pair fires the 16 float4 loads; sum_pair consumes (waitcnt lands here).
// ---------------------------------------------------------------------------
struct PB {
  float4 u[8];
  float4 v[8];
};

__device__ __forceinline__ void issue_pair(const float* __restrict__ a, PB& pb) {
  const float4* up = reinterpret_cast<const float4*>(a);
  const float4* vp = reinterpret_cast<const float4*>(a + KK);
#pragma unroll
  for (int q = 0; q < 8; ++q) pb.u[q] = up[q];
#pragma unroll
  for (int q = 0; q < 8; ++q) pb.v[q] = vp[q];
}

__device__ __forceinline__ void sum_pair(const PB& pb, float p[KK]) {
#pragma unroll
  for (int q = 0; q < 8; ++q) {
    p[4 * q + 0] = pb.u[q].x + pb.v[q].x;
    p[4 * q + 1] = pb.u[q].y + pb.v[q].y;
    p[4 * q + 2] = pb.u[q].z + pb.v[q].z;
    p[4 * q + 3] = pb.u[q].w + pb.v[q].w;
  }
}

// ---------------------------------------------------------------------------
// kern1: levels 1-3 (8 leaves -> 1 node). grid (256, 2) x 256 thr.
// Per-lane-K, zero LDS/barriers. Double-buffered pair prefetch: loads for
// pair n+1 are in flight while node n computes. Output stored transposed
// [node][k][batch] so every downstream access is coalesced.
// ---------------------------------------------------------------------------
__global__ __launch_bounds__(256, 2) void kern1(const float* __restrict__ x,
                                                const float* __restrict__ W,
                                                float* __restrict__ o) {
  const int tid = threadIdx.x;
  const int lane = tid & 63;
  const int wid = tid >> 6;
  const int chunk = blockIdx.x;  // 0..255
  const int b = blockIdx.y * 256 + wid * 64 + lane;

  const float* xb = x + (size_t)b * (DD * KK) + (size_t)chunk * 8 * KK;
  const float* WL1 = W + (size_t)(4 * chunk) * (KK * KK);
  const float* WL2 = W + (size_t)(1024 + 2 * chunk) * (KK * KK);
  const float* WL3 = W + (size_t)(1536 + chunk) * (KK * KK);

  PB A0, A1;
  issue_pair(xb + 0 * 64, A0);  // pair 0 (leaves 0,1)
  issue_pair(xb + 1 * 64, A1);  // pair 1 (leaves 2,3)

  float pA[KK], pB[KK], s01[KK], s23[KK];

  sum_pair(A0, pA);
  issue_pair(xb + 2 * 64, A0);  // pair 2 in flight during nodes 0,1
  node32(pA, WL1 + 0 * 1024);

  sum_pair(A1, pB);
  issue_pair(xb + 3 * 64, A1);  // pair 3 in flight
  node32(pB, WL1 + 1 * 1024);

#pragma unroll
  for (int j = 0; j < KK; ++j) s01[j] = pA[j] + pB[j];

  sum_pair(A0, pA);
  node32(pA, WL1 + 2 * 1024);
  sum_pair(A1, pB);
  node32(pB, WL1 + 3 * 1024);

#pragma unroll
  for (int j = 0; j < KK; ++j) s23[j] = pA[j] + pB[j];

  node32(s01, WL2 + 0 * 1024);
  node32(s23, WL2 + 1 * 1024);
#pragma unroll
  for (int j = 0; j < KK; ++j) s01[j] += s23[j];

  node32(s01, WL3);

  // transposed store: [chunk][k][b] -> coalesced 256B per dword-store
#pragma unroll
  for (int k = 0; k < KK; ++k)
    o[((size_t)chunk * KK + k) * BATCH + b] = s01[k];
}

// ---------------------------------------------------------------------------
// tail helpers: slabs are [k][batch] -> per-k dword loads are coalesced
// ---------------------------------------------------------------------------
__device__ __forceinline__ void pairsum_t(const float* __restrict__ s0,
                                          const float* __restrict__ s1, int b,
                                          float p[KK]) {
  float a0[KK], a1[KK];
#pragma unroll
  for (int k = 0; k < KK; ++k) a0[k] = s0[k * BATCH + b];
#pragma unroll
  for (int k = 0; k < KK; ++k) a1[k] = s1[k * BATCH + b];
#pragma unroll
  for (int k = 0; k < KK; ++k) p[k] = a0[k] + a1[k];
}

// 4 child slabs -> 1 output vector (two low-level nodes + one parent)
__device__ __forceinline__ void unit3(const float* __restrict__ in,
                                      const float* __restrict__ W, int c0,
                                      int wlo, int whi, int b, float r[KK]) {
  float p[KK], q[KK];
  pairsum_t(in + (size_t)(c0 + 0) * SLABF, in + (size_t)(c0 + 1) * SLABF, b, p);
  node32(p, W + (size_t)wlo * 1024);
  pairsum_t(in + (size_t)(c0 + 2) * SLABF, in + (size_t)(c0 + 3) * SLABF, b, q);
  node32(q, W + (size_t)(wlo + 1) * 1024);
#pragma unroll
  for (int j = 0; j < KK; ++j) p[j] += q[j];
  node32(p, W + (size_t)whi * 1024);
#pragma unroll
  for (int j = 0; j < KK; ++j) r[j] = p[j];
}

// ---------------------------------------------------------------------------
// ktail: the ENTIRE tail (levels 4-11 + mixture LSE) in ONE cooperative
// kernel. 128 blocks x 256 thr = 512 waves; phases separated by grid.sync().
// Co-residency: 0 LDS, modest VGPR -> 128 blocks trivially resident.
// ---------------------------------------------------------------------------
__global__ __launch_bounds__(256, 2) void ktail(
    const float* __restrict__ A, const float* __restrict__ W,
    const float* __restrict__ mixw, float* __restrict__ out,
    float* __restrict__ B1, float* __restrict__ B2, float* __restrict__ B3) {
  cg::grid_group grid = cg::this_grid();
  const int lane = threadIdx.x & 63;
  const int gw = (blockIdx.x << 2) | (threadIdx.x >> 6);  // 0..511

  {  // phase 1: L4-5, 64 units x 8 batch-groups = 512 waves (all active)
    const int u = gw >> 3;
    const int b = (gw & 7) * 64 + lane;
    float r[KK];
    unit3(A, W, 4 * u, 1792 + 2 * u, 1920 + u, b, r);
#pragma unroll
    for (int k = 0; k < KK; ++k) B1[(size_t)u * SLABF + k * BATCH + b] = r[k];
  }
  __threadfence();
  grid.sync();

  if (gw < 128) {  // phase 2: L6-7, 16 units
    const int u = gw >> 3;
    const int b = (gw & 7) * 64 + lane;
    float r[KK];
    unit3(B1, W, 4 * u, 1984 + 2 * u, 2016 + u, b, r);
#pragma unroll
    for (int k = 0; k < KK; ++k) B2[(size_t)u * SLABF + k * BATCH + b] = r[k];
  }
  __threadfence();
  grid.sync();

  if (gw < 32) {  // phase 3: L8-9, 4 units
    const int u = gw >> 3;
    const int b = (gw & 7) * 64 + lane;
    float r[KK];
    unit3(B2, W, 4 * u, 2032 + 2 * u, 2040 + u, b, r);
#pragma unroll
    for (int k = 0; k < KK; ++k) B3[(size_t)u * SLABF + k * BATCH + b] = r[k];
  }
  __threadfence();
  grid.sync();

  if (gw < 8) {  // phase 4: L10-11 + mixture logsumexp, 8 waves
    const int b = gw * 64 + lane;
    float r[KK];
    unit3(B3, W, 0, 2044, 2046, b, r);

    // log_softmax(mix_logw): uniform -> scalar loads
    float wv[KK];
#pragma unroll
    for (int i = 0; i < KK; ++i) wv[i] = mixw[i];
    float t[16];
#pragma unroll
    for (int i = 0; i < 16; ++i) t[i] = fmaxf(wv[2 * i], wv[2 * i + 1]);
#pragma unroll
    for (int s = 8; s >= 1; s >>= 1)
#pragma unroll
      for (int i = 0; i < s; ++i) t[i] = fmaxf(t[i], t[i + s]);
    const float wm = t[0];
    float ws = 0.0f;
#pragma unroll
    for (int i = 0; i < KK; ++i) ws += __expf(wv[i] - wm);
    const float lsew = __logf(ws) + wm;

    float f[KK];
#pragma unroll
    for (int j = 0; j < KK; ++j) f[j] = 2.0f * r[j] + (wv[j] - lsew);
#pragma unroll
    for (int i = 0; i < 16; ++i) t[i] = fmaxf(f[2 * i], f[2 * i + 1]);
#pragma unroll
    for (int s = 8; s >= 1; s >>= 1)
#pragma unroll
      for (int i = 0; i < s; ++i) t[i] = fmaxf(t[i], t[i + s]);
    const float m2 = t[0];
    float ss = 0.0f;
#pragma unroll
    for (int j = 0; j < KK; ++j) ss += __expf(f[j] - m2);
    out[b] = __logf(ss) + m2;
  }
}

// ---------------------------------------------------------------------------
extern "C" void kernel_launch(void* const* d_in, const int* in_sizes, int n_in,
                              void* d_out, int out_size, void* d_ws,
                              size_t ws_size, hipStream_t stream) {
  const float* x = (const float*)d_in[0];     // [512][2048][32]
  const float* W = (const float*)d_in[1];     // [2047][32][32]
  // d_in[2] = fold_idx: always (2f, 2f+1) pairs per level -> hardcoded
  const float* mixw = (const float*)d_in[3];  // [32]
  float* out = (float*)d_out;                 // [512]

  float* A = (float*)d_ws;                  // 256 slabs [node][k][batch]
  float* B1 = A + (size_t)256 * SLABF;      // 64 slabs
  float* B2 = B1 + (size_t)64 * SLABF;      // 16 slabs
  float* B3 = B2 + (size_t)16 * SLABF;      // 4 slabs

  kern1<<<dim3(256, 2), 256, 0, stream>>>(x, W, A);  // L1-3 -> A[256]

  void* args[] = {(void*)&A,  (void*)&W,  (void*)&mixw, (void*)&out,
                  (void*)&B1, (void*)&B2, (void*)&B3};
  hipLaunchCooperativeKernel((const void*)ktail, dim3(128), dim3(256), args, 0,
                             stream);  // L4-11 + LSE in one dispatch
}

// Round 3
// 626.063 us; speedup vs baseline: 1.3001x; 1.3001x over previous
//
#include <hip/hip_runtime.h>

#define KK 32
#define BATCH 512
#define DD 2048
#define SLABF (KK * BATCH)  // floats per node slab, layout [k][batch] (transposed)

// ---------------------------------------------------------------------------
// Per-lane full-K node: p[32] (registers) -> log_matmul_exp result, in place.
// W is wave-uniform -> scalar loads on the SMEM pipe; no LDS, no barriers.
// ---------------------------------------------------------------------------
__device__ __forceinline__ void node32(float p[KK], const float* __restrict__ Wn) {
  float t[16];
#pragma unroll
  for (int i = 0; i < 16; ++i) t[i] = fmaxf(p[2 * i], p[2 * i + 1]);
#pragma unroll
  for (int s = 8; s >= 1; s >>= 1)
#pragma unroll
    for (int i = 0; i < s; ++i) t[i] = fmaxf(t[i], t[i + s]);
  const float m = t[0];

#pragma unroll
  for (int i = 0; i < KK; ++i) p[i] = __expf(p[i] - m);

  float acc[KK];
#pragma unroll
  for (int j = 0; j < KK; ++j) acc[j] = 0.0f;

#pragma unroll
  for (int i = 0; i < KK; ++i) {
    const float ei = p[i];
#pragma unroll
    for (int j = 0; j < KK; ++j) acc[j] = fmaf(ei, Wn[i * KK + j], acc[j]);
  }

#pragma unroll
  for (int j = 0; j < KK; ++j) p[j] = __logf(acc[j]) + m;
}

// coalesced slab access: element k of batch b lives at s[k*BATCH + b]
__device__ __forceinline__ void slab_load(const float* __restrict__ s, int b,
                                          float a[KK]) {
#pragma unroll
  for (int k = 0; k < KK; ++k) a[k] = s[k * BATCH + b];
}

__device__ __forceinline__ void slab_store(float* __restrict__ s, int b,
                                           const float a[KK]) {
#pragma unroll
  for (int k = 0; k < KK; ++k) s[k * BATCH + b] = a[k];
}

// ---------------------------------------------------------------------------
// 2-level unit: 4 child slabs -> 1 output vector (in registers).
// Second pair's loads are issued before node 1 computes (latency overlap).
// wl0/wl1 = W tiles of the two lower nodes, wh = parent tile.
// ---------------------------------------------------------------------------
__device__ __forceinline__ void unit2(const float* __restrict__ in, int c0,
                                      const float* __restrict__ W, int wl0,
                                      int wh, int b, float r[KK]) {
  const float* s = in + (size_t)c0 * SLABF;
  float a0[KK], a1[KK];
  slab_load(s, b, a0);
  slab_load(s + SLABF, b, a1);
  float p[KK];
#pragma unroll
  for (int k = 0; k < KK; ++k) p[k] = a0[k] + a1[k];

  float b0[KK], b1[KK];  // issue pair-2 loads; they fly during node 1
  slab_load(s + 2 * (size_t)SLABF, b, b0);
  slab_load(s + 3 * (size_t)SLABF, b, b1);

  node32(p, W + (size_t)wl0 * 1024);

  float q[KK];
#pragma unroll
  for (int k = 0; k < KK; ++k) q[k] = b0[k] + b1[k];
  node32(q, W + (size_t)(wl0 + 1) * 1024);

#pragma unroll
  for (int k = 0; k < KK; ++k) p[k] += q[k];
  node32(p, W + (size_t)wh * 1024);
#pragma unroll
  for (int k = 0; k < KK; ++k) r[k] = p[k];
}

// ---------------------------------------------------------------------------
// kernA: levels 1-2 (4 leaves -> 1 L2 node). grid (512, 2) x 256 thr
// = 4096 waves (4/SIMD). Per lane: 512 B contiguous x read, 3 nodes.
// Output transposed [node][k][batch].
// ---------------------------------------------------------------------------
__global__ __launch_bounds__(256) void kernA(const float* __restrict__ x,
                                             const float* __restrict__ W,
                                             float* __restrict__ o) {
  const int tid = threadIdx.x;
  const int lane = tid & 63;
  const int wid = tid >> 6;
  const int c = blockIdx.x;  // L2 node 0..511
  const int b = blockIdx.y * 256 + wid * 64 + lane;

  const float4* xb = reinterpret_cast<const float4*>(
      x + (size_t)b * (DD * KK) + (size_t)c * 4 * KK);

  // issue all 32 float4 loads (4 leaves, contiguous per lane) up front
  float4 P0[16], P1[16];
#pragma unroll
  for (int q = 0; q < 16; ++q) P0[q] = xb[q];
#pragma unroll
  for (int q = 0; q < 16; ++q) P1[q] = xb[16 + q];

  float p[KK], q[KK];
#pragma unroll
  for (int t = 0; t < 8; ++t) {
    p[4 * t + 0] = P0[t].x + P0[8 + t].x;
    p[4 * t + 1] = P0[t].y + P0[8 + t].y;
    p[4 * t + 2] = P0[t].z + P0[8 + t].z;
    p[4 * t + 3] = P0[t].w + P0[8 + t].w;
  }
  node32(p, W + (size_t)(2 * c) * 1024);  // L1 node 2c (P1 still in flight)

#pragma unroll
  for (int t = 0; t < 8; ++t) {
    q[4 * t + 0] = P1[t].x + P1[8 + t].x;
    q[4 * t + 1] = P1[t].y + P1[8 + t].y;
    q[4 * t + 2] = P1[t].z + P1[8 + t].z;
    q[4 * t + 3] = P1[t].w + P1[8 + t].w;
  }
  node32(q, W + (size_t)(2 * c + 1) * 1024);  // L1 node 2c+1

#pragma unroll
  for (int k = 0; k < KK; ++k) p[k] += q[k];
  node32(p, W + (size_t)(1024 + c) * 1024);  // L2 node c

  slab_store(o + (size_t)c * SLABF, b, p);
}

// ---------------------------------------------------------------------------
// kernU: generic 2-level tail kernel. blockIdx.x = unit. wlo = level base of
// the lower level, whi = level base of the upper level.
// ---------------------------------------------------------------------------
__global__ __launch_bounds__(256) void kernU(const float* __restrict__ in,
                                             const float* __restrict__ W,
                                             float* __restrict__ o, int wlo,
                                             int whi) {
  const int tid = threadIdx.x;
  const int lane = tid & 63;
  const int wid = tid >> 6;
  const int u = blockIdx.x;
  const int b = blockIdx.y * 256 + wid * 64 + lane;

  float r[KK];
  unit2(in, 4 * u, W, wlo + 2 * u, whi + u, b, r);
  slab_store(o + (size_t)u * SLABF, b, r);
}

// ---------------------------------------------------------------------------
// kernE: levels 9-11 + mixture logsumexp. grid (1, 2) x 256 thr.
// ---------------------------------------------------------------------------
__global__ __launch_bounds__(256) void kernE(const float* __restrict__ in,
                                             const float* __restrict__ W,
                                             const float* __restrict__ mixw,
                                             float* __restrict__ out) {
  const int tid = threadIdx.x;
  const int lane = tid & 63;
  const int wid = tid >> 6;
  const int b = blockIdx.y * 256 + wid * 64 + lane;

  float r0[KK], r1[KK];
  unit2(in, 0, W, 2040, 2044, b, r0);  // L9 n0,n1 -> L10 n0
  unit2(in, 4, W, 2042, 2045, b, r1);  // L9 n2,n3 -> L10 n1
#pragma unroll
  for (int k = 0; k < KK; ++k) r0[k] += r1[k];
  node32(r0, W + (size_t)2046 * 1024);  // L11 root

  // log_softmax(mix_logw): wave-uniform -> scalar loads
  float wv[KK];
#pragma unroll
  for (int i = 0; i < KK; ++i) wv[i] = mixw[i];
  float t[16];
#pragma unroll
  for (int i = 0; i < 16; ++i) t[i] = fmaxf(wv[2 * i], wv[2 * i + 1]);
#pragma unroll
  for (int s = 8; s >= 1; s >>= 1)
#pragma unroll
    for (int i = 0; i < s; ++i) t[i] = fmaxf(t[i], t[i + s]);
  const float wm = t[0];
  float ws = 0.0f;
#pragma unroll
  for (int i = 0; i < KK; ++i) ws += __expf(wv[i] - wm);
  const float lsew = __logf(ws) + wm;

  // flat = 2*root + logw ; per-lane logsumexp over K
  float f[KK];
#pragma unroll
  for (int j = 0; j < KK; ++j) f[j] = 2.0f * r0[j] + (wv[j] - lsew);
#pragma unroll
  for (int i = 0; i < 16; ++i) t[i] = fmaxf(f[2 * i], f[2 * i + 1]);
#pragma unroll
  for (int s = 8; s >= 1; s >>= 1)
#pragma unroll
    for (int i = 0; i < s; ++i) t[i] = fmaxf(t[i], t[i + s]);
  const float m2 = t[0];
  float ss = 0.0f;
#pragma unroll
  for (int j = 0; j < KK; ++j) ss += __expf(f[j] - m2);
  out[b] = __logf(ss) + m2;
}

// ---------------------------------------------------------------------------
extern "C" void kernel_launch(void* const* d_in, const int* in_sizes, int n_in,
                              void* d_out, int out_size, void* d_ws,
                              size_t ws_size, hipStream_t stream) {
  const float* x = (const float*)d_in[0];     // [512][2048][32]
  const float* W = (const float*)d_in[1];     // [2047][32][32]
  // d_in[2] = fold_idx: always (2f, 2f+1) pairs per level -> hardcoded
  const float* mixw = (const float*)d_in[3];  // [32]
  float* out = (float*)d_out;                 // [512]

  float* S2 = (float*)d_ws;                  // 512 L2 slabs  (32 MB)
  float* S4 = S2 + (size_t)512 * SLABF;      // 128 L4 slabs  (8 MB)
  float* S6 = S4 + (size_t)128 * SLABF;      // 32  L6 slabs  (2 MB)
  float* S8 = S6 + (size_t)32 * SLABF;       // 8   L8 slabs  (0.5 MB)

  kernA<<<dim3(512, 2), 256, 0, stream>>>(x, W, S2);             // L1-2
  kernU<<<dim3(128, 2), 256, 0, stream>>>(S2, W, S4, 1536, 1792);  // L3-4
  kernU<<<dim3(32, 2), 256, 0, stream>>>(S4, W, S6, 1920, 1984);   // L5-6
  kernU<<<dim3(8, 2), 256, 0, stream>>>(S6, W, S8, 2016, 2032);    // L7-8
  kernE<<<dim3(1, 2), 256, 0, stream>>>(S8, W, mixw, out);         // L9-11+LSE
}

// Round 4
// 383.075 us; speedup vs baseline: 2.1248x; 1.6343x over previous
//
#include <hip/hip_runtime.h>

#define KK 32
#define BATCH 512
#define DD 2048
#define SLABF (KK * BATCH)  // floats per node slab, layout [k][batch]

// ---------------------------------------------------------------------------
// Cooperative W staging: coalesced float4 copy of nf4 float4s into LDS.
// ---------------------------------------------------------------------------
__device__ __forceinline__ void stagew(float* __restrict__ dstl,
                                       const float* __restrict__ src, int nf4,
                                       int tid, int nthr) {
  const float4* s4 = reinterpret_cast<const float4*>(src);
  float4* d4 = reinterpret_cast<float4*>(dstl);
  for (int i = tid; i < nf4; i += nthr) d4[i] = s4[i];
}

// ---------------------------------------------------------------------------
// Per-lane full-K node, W tile in LDS. Wave-uniform float4 rows -> LDS
// broadcast reads (conflict-free), statically addressed -> compiler can
// prefetch rows arbitrarily far ahead. No barriers, no cross-lane.
// ---------------------------------------------------------------------------
__device__ __forceinline__ void node32l(float p[KK], const float* __restrict__ Wl) {
  float t[16];
#pragma unroll
  for (int i = 0; i < 16; ++i) t[i] = fmaxf(p[2 * i], p[2 * i + 1]);
#pragma unroll
  for (int s = 8; s >= 1; s >>= 1)
#pragma unroll
    for (int i = 0; i < s; ++i) t[i] = fmaxf(t[i], t[i + s]);
  const float m = t[0];

#pragma unroll
  for (int i = 0; i < KK; ++i) p[i] = __expf(p[i] - m);

  float acc[KK];
#pragma unroll
  for (int j = 0; j < KK; ++j) acc[j] = 0.0f;

  const float4* W4 = reinterpret_cast<const float4*>(Wl);
#pragma unroll
  for (int i = 0; i < KK; ++i) {
    const float ei = p[i];
#pragma unroll
    for (int q = 0; q < 8; ++q) {
      const float4 w = W4[i * 8 + q];
      acc[4 * q + 0] = fmaf(ei, w.x, acc[4 * q + 0]);
      acc[4 * q + 1] = fmaf(ei, w.y, acc[4 * q + 1]);
      acc[4 * q + 2] = fmaf(ei, w.z, acc[4 * q + 2]);
      acc[4 * q + 3] = fmaf(ei, w.w, acc[4 * q + 3]);
    }
  }

#pragma unroll
  for (int j = 0; j < KK; ++j) p[j] = __logf(acc[j]) + m;
}

// coalesced slab access: element k of batch b lives at s[k*BATCH + b]
__device__ __forceinline__ void slab_load(const float* __restrict__ s, int b,
                                          float a[KK]) {
#pragma unroll
  for (int k = 0; k < KK; ++k) a[k] = s[k * BATCH + b];
}

__device__ __forceinline__ void slab_store(float* __restrict__ s, int b,
                                           const float a[KK]) {
#pragma unroll
  for (int k = 0; k < KK; ++k) s[k * BATCH + b] = a[k];
}

// ---------------------------------------------------------------------------
// unit7: 3 tree levels, 8 child slabs -> 1 output vector (registers).
// Loads for the next pair are issued before the current node computes.
// WL holds 7 tiles: [0..3]=low level, [4..5]=mid, [6]=top.
// ---------------------------------------------------------------------------
__device__ __forceinline__ void unit7(const float* __restrict__ in,
                                      const float* __restrict__ WL, int b,
                                      float r[KK]) {
  float u[KK], v[KK], A[KK], Bv[KK], C[KK], Dv[KK];
  slab_load(in + 0 * (size_t)SLABF, b, u);
  slab_load(in + 1 * (size_t)SLABF, b, v);
#pragma unroll
  for (int k = 0; k < KK; ++k) A[k] = u[k] + v[k];
  slab_load(in + 2 * (size_t)SLABF, b, u);  // fly during node 0
  slab_load(in + 3 * (size_t)SLABF, b, v);
  node32l(A, WL + 0 * 1024);

#pragma unroll
  for (int k = 0; k < KK; ++k) Bv[k] = u[k] + v[k];
  slab_load(in + 4 * (size_t)SLABF, b, u);  // fly during node 1
  slab_load(in + 5 * (size_t)SLABF, b, v);
  node32l(Bv, WL + 1 * 1024);

#pragma unroll
  for (int k = 0; k < KK; ++k) C[k] = u[k] + v[k];
  slab_load(in + 6 * (size_t)SLABF, b, u);  // fly during node 2
  slab_load(in + 7 * (size_t)SLABF, b, v);
  node32l(C, WL + 2 * 1024);

#pragma unroll
  for (int k = 0; k < KK; ++k) Dv[k] = u[k] + v[k];
  node32l(Dv, WL + 3 * 1024);

#pragma unroll
  for (int k = 0; k < KK; ++k) A[k] += Bv[k];
  node32l(A, WL + 4 * 1024);
#pragma unroll
  for (int k = 0; k < KK; ++k) C[k] += Dv[k];
  node32l(C, WL + 5 * 1024);
#pragma unroll
  for (int k = 0; k < KK; ++k) A[k] += C[k];
  node32l(A, WL + 6 * 1024);
#pragma unroll
  for (int k = 0; k < KK; ++k) r[k] = A[k];
}

// ---------------------------------------------------------------------------
// kernA: levels 1-2 (4 leaves -> 1 L2 node). grid (512, 2) x 256 thr
// = 4096 waves. VGPR kept <=128 (one leaf-pair buffered at a time) so
// occupancy reaches 4 waves/SIMD. W tiles (12 KB) staged in LDS.
// ---------------------------------------------------------------------------
__global__ __launch_bounds__(256, 4) void kernA(const float* __restrict__ x,
                                                const float* __restrict__ W,
                                                float* __restrict__ o) {
  __shared__ __align__(16) float WL[3 * 1024];
  const int tid = threadIdx.x;
  const int c = blockIdx.x;  // L2 node 0..511
  const int b = blockIdx.y * 256 + tid;

  stagew(WL, W + (size_t)(2 * c) * 1024, 512, tid, 256);        // L1 tiles 2c,2c+1
  stagew(WL + 2048, W + (size_t)(1024 + c) * 1024, 256, tid, 256);  // L2 tile c
  __syncthreads();

  const float4* xb = reinterpret_cast<const float4*>(
      x + (size_t)b * (DD * KK) + (size_t)c * 128);

  float4 P[16];
  float a[KK], c2[KK];

  // pair 0 (leaves 0,1)
#pragma unroll
  for (int q = 0; q < 16; ++q) P[q] = xb[q];
#pragma unroll
  for (int q = 0; q < 8; ++q) {
    a[4 * q + 0] = P[q].x + P[8 + q].x;
    a[4 * q + 1] = P[q].y + P[8 + q].y;
    a[4 * q + 2] = P[q].z + P[8 + q].z;
    a[4 * q + 3] = P[q].w + P[8 + q].w;
  }
  node32l(a, WL);  // L1 node 2c

  // pair 1 (leaves 2,3)
#pragma unroll
  for (int q = 0; q < 16; ++q) P[q] = xb[16 + q];
#pragma unroll
  for (int q = 0; q < 8; ++q) {
    c2[4 * q + 0] = P[q].x + P[8 + q].x;
    c2[4 * q + 1] = P[q].y + P[8 + q].y;
    c2[4 * q + 2] = P[q].z + P[8 + q].z;
    c2[4 * q + 3] = P[q].w + P[8 + q].w;
  }
  node32l(c2, WL + 1024);  // L1 node 2c+1

#pragma unroll
  for (int k = 0; k < KK; ++k) a[k] += c2[k];
  node32l(a, WL + 2048);  // L2 node c

  slab_store(o + (size_t)c * SLABF, b, a);
}

// ---------------------------------------------------------------------------
// kernU: 3 tail levels (8 slabs -> 1). grid (units, 2) x 256 thr.
// base4/base2/base1 = W level bases of the three levels.
// ---------------------------------------------------------------------------
__global__ __launch_bounds__(256) void kernU(const float* __restrict__ in,
                                             const float* __restrict__ W,
                                             float* __restrict__ o, int base4,
                                             int base2, int base1) {
  __shared__ __align__(16) float WL[7 * 1024];
  const int tid = threadIdx.x;
  const int u = blockIdx.x;
  const int b = blockIdx.y * 256 + tid;

  stagew(WL, W + (size_t)(base4 + 4 * u) * 1024, 1024, tid, 256);
  stagew(WL + 4096, W + (size_t)(base2 + 2 * u) * 1024, 512, tid, 256);
  stagew(WL + 6144, W + (size_t)(base1 + u) * 1024, 256, tid, 256);
  __syncthreads();

  float r[KK];
  unit7(in + (size_t)(8 * u) * SLABF, WL, b, r);
  slab_store(o + (size_t)u * SLABF, b, r);
}

// ---------------------------------------------------------------------------
// kernD: levels 9-11 + mixture logsumexp. grid (1, 2) x 256 thr.
// ---------------------------------------------------------------------------
__global__ __launch_bounds__(256) void kernD(const float* __restrict__ in,
                                             const float* __restrict__ W,
                                             const float* __restrict__ mixw,
                                             float* __restrict__ out) {
  __shared__ __align__(16) float WL[7 * 1024];
  const int tid = threadIdx.x;
  const int b = blockIdx.y * 256 + tid;

  stagew(WL, W + (size_t)2040 * 1024, 1024, tid, 256);       // L9 x4
  stagew(WL + 4096, W + (size_t)2044 * 1024, 512, tid, 256);  // L10 x2
  stagew(WL + 6144, W + (size_t)2046 * 1024, 256, tid, 256);  // L11
  __syncthreads();

  float r[KK];
  unit7(in, WL, b, r);

  // log_softmax(mix_logw): wave-uniform -> scalar loads
  float wv[KK];
#pragma unroll
  for (int i = 0; i < KK; ++i) wv[i] = mixw[i];
  float t[16];
#pragma unroll
  for (int i = 0; i < 16; ++i) t[i] = fmaxf(wv[2 * i], wv[2 * i + 1]);
#pragma unroll
  for (int s = 8; s >= 1; s >>= 1)
#pragma unroll
    for (int i = 0; i < s; ++i) t[i] = fmaxf(t[i], t[i + s]);
  const float wm = t[0];
  float ws = 0.0f;
#pragma unroll
  for (int i = 0; i < KK; ++i) ws += __expf(wv[i] - wm);
  const float lsew = __logf(ws) + wm;

  // flat = 2*root + logw ; per-lane logsumexp over K
  float f[KK];
#pragma unroll
  for (int j = 0; j < KK; ++j) f[j] = 2.0f * r[j] + (wv[j] - lsew);
#pragma unroll
  for (int i = 0; i < 16; ++i) t[i] = fmaxf(f[2 * i], f[2 * i + 1]);
#pragma unroll
  for (int s = 8; s >= 1; s >>= 1)
#pragma unroll
    for (int i = 0; i < s; ++i) t[i] = fmaxf(t[i], t[i + s]);
  const float m2 = t[0];
  float ss = 0.0f;
#pragma unroll
  for (int j = 0; j < KK; ++j) ss += __expf(f[j] - m2);
  out[b] = __logf(ss) + m2;
}

// ---------------------------------------------------------------------------
extern "C" void kernel_launch(void* const* d_in, const int* in_sizes, int n_in,
                              void* d_out, int out_size, void* d_ws,
                              size_t ws_size, hipStream_t stream) {
  const float* x = (const float*)d_in[0];     // [512][2048][32]
  const float* W = (const float*)d_in[1];     // [2047][32][32]
  // d_in[2] = fold_idx: always (2f, 2f+1) pairs per level -> hardcoded
  const float* mixw = (const float*)d_in[3];  // [32]
  float* out = (float*)d_out;                 // [512]

  float* S2 = (float*)d_ws;                 // 512 L2 slabs (32 MB)
  float* S5 = S2 + (size_t)512 * SLABF;     // 64 L5 slabs (4 MB)
  float* S8 = S5 + (size_t)64 * SLABF;      // 8 L8 slabs (0.5 MB)

  kernA<<<dim3(512, 2), 256, 0, stream>>>(x, W, S2);              // L1-2
  kernU<<<dim3(64, 2), 256, 0, stream>>>(S2, W, S5, 1536, 1792, 1920);  // L3-5
  kernU<<<dim3(8, 2), 256, 0, stream>>>(S5, W, S8, 1984, 2016, 2032);   // L6-8
  kernD<<<dim3(1, 2), 256, 0, stream>>>(S8, W, mixw, out);              // L9-11+LSE
}

// Round 6
// 246.838 us; speedup vs baseline: 3.2975x; 1.5519x over previous
//
#include <hip/hip_runtime.h>

#define KK 32
#define BATCH 512
#define DD 2048
#define ESTRIDE 36          // floats; 16B-aligned rows, 0 conflicts measured
#define NUNIT (KK * BATCH)  // floats per node slab [K][BATCH]

// ---------------------------------------------------------------------------
// helpers
// ---------------------------------------------------------------------------
__device__ __forceinline__ float max8(const float p[8]) {
  const float a0 = fmaxf(p[0], p[1]), a1 = fmaxf(p[2], p[3]);
  const float a2 = fmaxf(p[4], p[5]), a3 = fmaxf(p[6], p[7]);
  return fmaxf(fmaxf(a0, a1), fmaxf(a2, a3));
}
__device__ __forceinline__ float max4pm(const float* pm, int lane) {
  return fmaxf(fmaxf(pm[lane], pm[65 + lane]),
               fmaxf(pm[130 + lane], pm[195 + lane]));
}
__device__ __forceinline__ void write_e(float* __restrict__ E, int lane,
                                        int j0, const float p[8], float m) {
  float4* ew = reinterpret_cast<float4*>(E + lane * ESTRIDE + j0);
  ew[0] = make_float4(__expf(p[0] - m), __expf(p[1] - m), __expf(p[2] - m),
                      __expf(p[3] - m));
  ew[1] = make_float4(__expf(p[4] - m), __expf(p[5] - m), __expf(p[6] - m),
                      __expf(p[7] - m));
}
__device__ __forceinline__ void addv8(const float a[8], const float b[8],
                                      float o[8]) {
#pragma unroll
  for (int j = 0; j < 8; ++j) o[j] = a[j] + b[j];
}

#define MAC8(acc, e, w0, w1)                                   \
  acc[0] = fmaf(e, w0.x, acc[0]); acc[1] = fmaf(e, w0.y, acc[1]); \
  acc[2] = fmaf(e, w0.z, acc[2]); acc[3] = fmaf(e, w0.w, acc[3]); \
  acc[4] = fmaf(e, w1.x, acc[4]); acc[5] = fmaf(e, w1.y, acc[5]); \
  acc[6] = fmaf(e, w1.z, acc[6]); acc[7] = fmaf(e, w1.w, acc[7]);

// ---------------------------------------------------------------------------
// PAIR of independent nodes sharing one barrier pair. Block = 4 waves,
// wave jg owns outputs j in [jg*8, jg*8+8), lane = batch. Interleaved MAC:
// two independent FMA chains (2x ILP), one #pragma unroll 1 q-loop (R4
// lesson: full unroll -> VGPR 168 -> occupancy collapse).
// NST: W-restage ops folded into the B1->B2 window (slots being restaged are
// guaranteed dead: all waves passed B1 => previous pair's MAC is complete).
// ---------------------------------------------------------------------------
template <int NST>
__device__ __forceinline__ void node8_pairT(
    const float pa[8], const float pb[8], const float* __restrict__ Wa,
    const float* __restrict__ Wb, float* __restrict__ Ea,
    float* __restrict__ Eb, float* __restrict__ pm, int jg, int lane, int j0,
    float oa[8], float ob[8], int tid, float4* __restrict__ rdst, float4 rva,
    float4 rvb) {
  pm[jg * 65 + lane] = max8(pa);
  pm[260 + jg * 65 + lane] = max8(pb);
  __syncthreads();  // B1: pm visible (also fences prev step's E + W-slot reads)
  const float ma = max4pm(pm, lane);
  const float mb = max4pm(pm + 260, lane);
  write_e(Ea, lane, j0, pa, ma);
  write_e(Eb, lane, j0, pb, mb);
  if constexpr (NST >= 1) rdst[tid] = rva;        // restage W tile (ds_write
  if constexpr (NST >= 2) rdst[256 + tid] = rvb;  //  only; load issued at entry)
  __syncthreads();  // B2: e + restaged W visible

  const float4* era = reinterpret_cast<const float4*>(Ea + lane * ESTRIDE);
  const float4* erb = reinterpret_cast<const float4*>(Eb + lane * ESTRIDE);
  const float4* WLa = reinterpret_cast<const float4*>(Wa) + (j0 >> 2);
  const float4* WLb = reinterpret_cast<const float4*>(Wb) + (j0 >> 2);

  float acca[8], accb[8];
#pragma unroll
  for (int j = 0; j < 8; ++j) { acca[j] = 0.0f; accb[j] = 0.0f; }

#pragma unroll 1
  for (int q = 0; q < 8; ++q) {
    const float4 eva = era[q];
    const float4 evb = erb[q];
    const int i0 = 4 * q;
    {
      const float4 w0 = WLa[(i0 + 0) * 8], w1 = WLa[(i0 + 0) * 8 + 1];
      const float4 v0 = WLb[(i0 + 0) * 8], v1 = WLb[(i0 + 0) * 8 + 1];
      MAC8(acca, eva.x, w0, w1) MAC8(accb, evb.x, v0, v1)
    }
    {
      const float4 w0 = WLa[(i0 + 1) * 8], w1 = WLa[(i0 + 1) * 8 + 1];
      const float4 v0 = WLb[(i0 + 1) * 8], v1 = WLb[(i0 + 1) * 8 + 1];
      MAC8(acca, eva.y, w0, w1) MAC8(accb, evb.y, v0, v1)
    }
    {
      const float4 w0 = WLa[(i0 + 2) * 8], w1 = WLa[(i0 + 2) * 8 + 1];
      const float4 v0 = WLb[(i0 + 2) * 8], v1 = WLb[(i0 + 2) * 8 + 1];
      MAC8(acca, eva.z, w0, w1) MAC8(accb, evb.z, v0, v1)
    }
    {
      const float4 w0 = WLa[(i0 + 3) * 8], w1 = WLa[(i0 + 3) * 8 + 1];
      const float4 v0 = WLb[(i0 + 3) * 8], v1 = WLb[(i0 + 3) * 8 + 1];
      MAC8(acca, eva.w, w0, w1) MAC8(accb, evb.w, v0, v1)
    }
  }
#pragma unroll
  for (int j = 0; j < 8; ++j) {
    oa[j] = __logf(acca[j]) + ma;
    ob[j] = __logf(accb[j]) + mb;
  }
}

// single node (tree roots of each fused group)
__device__ __forceinline__ void node8L(const float p8[8],
                                       const float* __restrict__ Wt,
                                       float* __restrict__ E,
                                       float* __restrict__ pm, int jg,
                                       int lane, int j0, float o8[8]) {
  pm[jg * 65 + lane] = max8(p8);
  __syncthreads();
  const float m = max4pm(pm, lane);
  write_e(E, lane, j0, p8, m);
  __syncthreads();

  const float4* er = reinterpret_cast<const float4*>(E + lane * ESTRIDE);
  const float4* WL = reinterpret_cast<const float4*>(Wt) + (j0 >> 2);
  float acc[8];
#pragma unroll
  for (int j = 0; j < 8; ++j) acc[j] = 0.0f;
#pragma unroll 1
  for (int q = 0; q < 8; ++q) {
    const float4 ev = er[q];
    const int i0 = 4 * q;
    const float4 wa0 = WL[(i0 + 0) * 8], wa1 = WL[(i0 + 0) * 8 + 1];
    const float4 wb0 = WL[(i0 + 1) * 8], wb1 = WL[(i0 + 1) * 8 + 1];
    const float4 wc0 = WL[(i0 + 2) * 8], wc1 = WL[(i0 + 2) * 8 + 1];
    const float4 wd0 = WL[(i0 + 3) * 8], wd1 = WL[(i0 + 3) * 8 + 1];
    MAC8(acc, ev.x, wa0, wa1) MAC8(acc, ev.y, wb0, wb1)
    MAC8(acc, ev.z, wc0, wc1) MAC8(acc, ev.w, wd0, wd1)
  }
#pragma unroll
  for (int j = 0; j < 8; ++j) o8[j] = __logf(acc[j]) + m;
}

__device__ __forceinline__ void pairload_x(const float* __restrict__ xb,
                                           int leaf, int j0, float p[8]) {
  const float4* u = reinterpret_cast<const float4*>(xb + leaf * KK + j0);
  const float4* v = reinterpret_cast<const float4*>(xb + (leaf + 1) * KK + j0);
  const float4 u0 = u[0], u1 = u[1], v0 = v[0], v1 = v[1];
  p[0] = u0.x + v0.x; p[1] = u0.y + v0.y; p[2] = u0.z + v0.z; p[3] = u0.w + v0.w;
  p[4] = u1.x + v1.x; p[5] = u1.y + v1.y; p[6] = u1.z + v1.z; p[7] = u1.w + v1.w;
}

__device__ __forceinline__ void pairload_n(const float* __restrict__ in,
                                           int node, int j0, int b, float p[8]) {
  const float* p0 = in + (size_t)node * NUNIT + (size_t)j0 * BATCH + b;
  const float* p1 = p0 + NUNIT;
#pragma unroll
  for (int k = 0; k < 8; ++k) p[k] = p0[k * BATCH] + p1[k * BATCH];
}

// ---------------------------------------------------------------------------
// kern1: levels 1-3 (8 leaves -> 1 node per block-chunk). grid (256, 8).
// 8 barriers/block. LDS diet vs r0: W_lds 7 tiles (28 KB) -> 4 slots (16 KB);
// L2/L3 tiles are held in 3 float4/thread registers (loaded up-front, one
// pipelined global latency) and ds-written into recycled slots inside the
// existing B1->B2 windows. Total LDS 36.9 KB -> 4 blocks/CU (was 48.6 KB ->
// 3 blocks/CU), 16 waves/CU, matching __launch_bounds__(256,4).
// ---------------------------------------------------------------------------
__global__ __launch_bounds__(256, 4) void kern1(const float* __restrict__ x,
                                                const float* __restrict__ W,
                                                float* __restrict__ o) {
  __shared__ __align__(16) float W_lds[4 * KK * KK];
  __shared__ __align__(16) float Ea[64 * ESTRIDE];
  __shared__ __align__(16) float Eb[64 * ESTRIDE];
  __shared__ float pm[2 * 260];
  const int tid = threadIdx.x;
  const int lane = tid & 63;
  const int jg = __builtin_amdgcn_readfirstlane(tid >> 6);
  const int j0 = jg * 8;
  const int b = blockIdx.y * 64 + lane;
  const int chunk = blockIdx.x;
  const int c4 = chunk * 4, c2 = chunk * 2;

  // stage 4 L1 tiles into LDS; park L2/L3 tiles in registers (12 VGPR)
  const float4* W4 = reinterpret_cast<const float4*>(W);
  float4* WL4 = reinterpret_cast<float4*>(W_lds);
  WL4[tid]       = W4[(size_t)(c4 + 0) * 256 + tid];  // slot 0: L1 n 4c
  WL4[256 + tid] = W4[(size_t)(c4 + 1) * 256 + tid];  // slot 1: L1 n 4c+1
  WL4[512 + tid] = W4[(size_t)(c4 + 2) * 256 + tid];  // slot 2: L1 n 4c+2
  WL4[768 + tid] = W4[(size_t)(c4 + 3) * 256 + tid];  // slot 3: L1 n 4c+3
  const float4 wr4 = W4[(size_t)(1024 + c2 + 0) * 256 + tid];  // L2a
  const float4 wr5 = W4[(size_t)(1024 + c2 + 1) * 256 + tid];  // L2b
  const float4 wr6 = W4[(size_t)(1536 + chunk) * 256 + tid];   // L3

  // all x loads for this chunk issued up front (overlap with first MAC)
  const float* xb = x + (size_t)b * (DD * KK) + (size_t)chunk * 8 * KK;
  float pA0[8], pB0[8], pA1[8], pB1[8];
  pairload_x(xb, 0, j0, pA0);
  pairload_x(xb, 2, j0, pB0);
  pairload_x(xb, 4, j0, pA1);
  pairload_x(xb, 6, j0, pB1);

  float n0[8], n1[8], n2[8], n3[8], m0[8], m1[8], o8[8], p[8], q[8];

  // pair 1: L1 nodes 4c,4c+1 on slots 0,1 (no restage; all 4 slots live)
  node8_pairT<0>(pA0, pB0, W_lds + 0 * 1024, W_lds + 1 * 1024, Ea, Eb, pm, jg,
                 lane, j0, n0, n1, tid, nullptr, wr4, wr4);
  // pair 2: L1 nodes 4c+2,4c+3 on slots 2,3; restage slots 0,1 <- L2 tiles
  node8_pairT<2>(pA1, pB1, W_lds + 2 * 1024, W_lds + 3 * 1024, Ea, Eb, pm, jg,
                 lane, j0, n2, n3, tid, WL4, wr4, wr5);
  addv8(n0, n1, p);
  addv8(n2, n3, q);
  // pair 3: L2 nodes on slots 0,1; restage slot 2 <- L3 tile
  node8_pairT<1>(p, q, W_lds + 0 * 1024, W_lds + 1 * 1024, Ea, Eb, pm, jg,
                 lane, j0, m0, m1, tid, WL4 + 512, wr6, wr6);
  addv8(m0, m1, p);
  // root: L3 node on slot 2
  node8L(p, W_lds + 2 * 1024, Ea, pm, jg, lane, j0, o8);

#pragma unroll
  for (int j = 0; j < 8; ++j)
    o[(size_t)chunk * NUNIT + (size_t)(j0 + j) * BATCH + b] = o8[j];
}

// ---------------------------------------------------------------------------
// kernT: TWO tree levels (4 child nodes -> 1). grid (F_hi, 8) x 256.
// 3 nodes, 4 barriers. lo/hi are W offsets of the two levels.
// ---------------------------------------------------------------------------
__global__ __launch_bounds__(256, 4) void kernT(const float* __restrict__ in,
                                                const float* __restrict__ W,
                                                float* __restrict__ o, int lo,
                                                int hi) {
  __shared__ __align__(16) float W_lds[3 * KK * KK];
  __shared__ __align__(16) float Ea[64 * ESTRIDE];
  __shared__ __align__(16) float Eb[64 * ESTRIDE];
  __shared__ float pm[2 * 260];
  const int tid = threadIdx.x;
  const int lane = tid & 63;
  const int jg = __builtin_amdgcn_readfirstlane(tid >> 6);
  const int j0 = jg * 8;
  const int b = blockIdx.y * 64 + lane;
  const int n = blockIdx.x;

  const float4* W4 = reinterpret_cast<const float4*>(W);
  float4* WL4 = reinterpret_cast<float4*>(W_lds);
  WL4[tid]       = W4[(size_t)(lo + 2 * n + 0) * 256 + tid];
  WL4[256 + tid] = W4[(size_t)(lo + 2 * n + 1) * 256 + tid];
  WL4[512 + tid] = W4[(size_t)(hi + n) * 256 + tid];

  float pa[8], pb[8], r0[8], r1[8], p[8], o8[8];
  pairload_n(in, 4 * n + 0, j0, b, pa);
  pairload_n(in, 4 * n + 2, j0, b, pb);
  node8_pairT<0>(pa, pb, W_lds, W_lds + 1024, Ea, Eb, pm, jg, lane, j0, r0,
                 r1, tid, nullptr, make_float4(0, 0, 0, 0),
                 make_float4(0, 0, 0, 0));
  addv8(r0, r1, p);
  node8L(p, W_lds + 2048, Ea, pm, jg, lane, j0, o8);

#pragma unroll
  for (int j = 0; j < 8; ++j)
    o[(size_t)n * NUNIT + (size_t)(j0 + j) * BATCH + b] = o8[j];
}

// ---------------------------------------------------------------------------
// kernF: levels 10-11 (4 -> 1) + mixture logsumexp. grid (1, 8) x 256.
// ---------------------------------------------------------------------------
__global__ __launch_bounds__(256, 4) void kernF(const float* __restrict__ in,
                                                const float* __restrict__ W,
                                                const float* __restrict__ mixw,
                                                float* __restrict__ out) {
  __shared__ __align__(16) float W_lds[3 * KK * KK];
  __shared__ __align__(16) float Ea[64 * ESTRIDE];
  __shared__ __align__(16) float Eb[64 * ESTRIDE];
  __shared__ float pm[2 * 260];
  const int tid = threadIdx.x;
  const int lane = tid & 63;
  const int jg = __builtin_amdgcn_readfirstlane(tid >> 6);
  const int j0 = jg * 8;
  const int b = blockIdx.y * 64 + lane;

  const float4* W4 = reinterpret_cast<const float4*>(W);
  float4* WL4 = reinterpret_cast<float4*>(W_lds);
  WL4[tid]       = W4[(size_t)2044 * 256 + tid];
  WL4[256 + tid] = W4[(size_t)2045 * 256 + tid];
  WL4[512 + tid] = W4[(size_t)2046 * 256 + tid];

  float pa[8], pb[8], r0[8], r1[8], p[8], o8[8];
  pairload_n(in, 0, j0, b, pa);
  pairload_n(in, 2, j0, b, pb);
  node8_pairT<0>(pa, pb, W_lds, W_lds + 1024, Ea, Eb, pm, jg, lane, j0, r0,
                 r1, tid, nullptr, make_float4(0, 0, 0, 0),
                 make_float4(0, 0, 0, 0));
  addv8(r0, r1, p);
  node8L(p, W_lds + 2048, Ea, pm, jg, lane, j0, o8);

  // log_softmax of mix_logw (wave-uniform -> scalar loads)
  float wv32[KK];
#pragma unroll
  for (int i = 0; i < KK; ++i) wv32[i] = mixw[i];
  float t[KK];
#pragma unroll
  for (int i = 0; i < KK; ++i) t[i] = wv32[i];
#pragma unroll
  for (int s = KK / 2; s >= 1; s >>= 1)
#pragma unroll
    for (int i = 0; i < s; ++i) t[i] = fmaxf(t[i], t[i + s]);
  const float wm = t[0];
  float ws = 0.0f;
#pragma unroll
  for (int i = 0; i < KK; ++i) ws += __expf(wv32[i] - wm);
  const float lsew = __logf(ws) + wm;

  float t8[8];
#pragma unroll
  for (int j = 0; j < 8; ++j) t8[j] = 2.0f * o8[j] + (wv32[j0 + j] - lsew);
  __syncthreads();
  pm[jg * 65 + lane] = max8(t8);
  __syncthreads();
  const float m2 = max4pm(pm, lane);
  float ss = 0.0f;
#pragma unroll
  for (int j = 0; j < 8; ++j) ss += __expf(t8[j] - m2);
  __syncthreads();
  pm[jg * 65 + lane] = ss;
  __syncthreads();
  if (jg == 0) {
    const float s4 = (pm[lane] + pm[65 + lane]) + (pm[130 + lane] + pm[195 + lane]);
    out[b] = __logf(s4) + m2;
  }
}

// ---------------------------------------------------------------------------
extern "C" void kernel_launch(void* const* d_in, const int* in_sizes, int n_in,
                              void* d_out, int out_size, void* d_ws,
                              size_t ws_size, hipStream_t stream) {
  const float* x = (const float*)d_in[0];     // [512][2048][32]
  const float* W = (const float*)d_in[1];     // [2047][32][32]
  // d_in[2] = fold_idx: always (2f, 2f+1) pairs per level -> hardcoded
  const float* mixw = (const float*)d_in[3];  // [32]
  float* out = (float*)d_out;                 // [512]

  float* A = (float*)d_ws;              // up to 256 node units (16.8 MB)
  float* Bb = A + (size_t)256 * NUNIT;  // up to 64 node units

  kern1<<<dim3(256, 8), 256, 0, stream>>>(x, W, A);              // L1-3 -> A[256]
  kernT<<<dim3(64, 8), 256, 0, stream>>>(A, W, Bb, 1792, 1920);  // L4-5 -> B[64]
  kernT<<<dim3(16, 8), 256, 0, stream>>>(Bb, W, A, 1984, 2016);  // L6-7 -> A[16]
  kernT<<<dim3(4, 8), 256, 0, stream>>>(A, W, Bb, 2032, 2040);   // L8-9 -> B[4]
  kernF<<<dim3(1, 8), 256, 0, stream>>>(Bb, W, mixw, out);       // L10-11 + LSE
}